// Round 11
// baseline (274.350 us; speedup 1.0000x reference)
//
#include <hip/hip_runtime.h>
#include <math.h>
#include <stdint.h>

// pix_attn R10: R9 minus the scheduling fences.
//  - R9 diagnosis: per-wave latency-bound (waves stalled ~90%; VALU pipe only
//    ~17us of a 68us wall). The ~40 sched_barrier(0) fences — installed to
//    fight spills back when the VGPR cap was 64-128 — serialize every phase
//    into issue->drain->compute segments and forbid cross-group overlap.
//    Cap is 256 now (256-thr block, 1 wave/SIMD floor), settled use 100.
//  - This round: remove ALL mid-phase fences; let the compiler hoist
//    ds_read_b128 groups and s_load weight batches 2-3 groups deep.
//    Diagnostic: WRITE_SIZE must stay ~16 MB (no spill), VGPR 150-230.
//  - Tile: [g=ch/8][6 rows][18 cols][4 dwords], dword = bf16(8g+2w)|bf16(+1).
//    One ds_read_b128 = 8 channels. Rows are 288B apart -> <=2-way banks.
//  - Rest: grid 1024 (2 blocks/tile, 4 heads each), memset+unsafeAtomicAdd
//    merge, u-trick / y-trick, wave = head, bf16 pack error ~2e-3 << 7.3e-3.
//
// Scramble: f = 9*ch + l ; t = f>>6, c = f&63, (wi,wj) = (l/3, l%3).

#define GS 432      // group stride (words) = 6 rows * 72
#define RS 72       // row stride (words) = 18 cols * 4

__global__ __launch_bounds__(256, 1) void pix_attn_main(
    const float* __restrict__ x,
    const float* __restrict__ W_qk,
    const float* __restrict__ b_qk,
    const float* __restrict__ W_kv,
    const float* __restrict__ b_kv,
    const float* __restrict__ W_proj,
    const float* __restrict__ b_proj,
    float* __restrict__ out)
{
    __shared__ uint32_t smem[8 * GS];    // 13824 B packed tile; pre_s after

    const int tid = threadIdx.x;
    // swizzle: ids j and j+8 are the two head-groups of one tile (same XCD)
    const int j    = blockIdx.x;
    const int g_   = j >> 4;
    const int tile = g_ * 8 + (j & 7);
    const int hg   = (j >> 3) & 1;
    const int bb   = tile >> 6;
    const int t_id = tile & 63;
    const int h0r  = (t_id >> 2) << 2;
    const int w0c  = (t_id & 3) << 4;

    // ---- stage packed tile: word(g,r,cc,w) = bf16(ch=8g+2w)|bf16(+1) ----
    const float* xb = x + (size_t)bb * (64 * 64 * 64);
    for (int it = 0; it < 14; ++it) {
        int idx = it * 256 + tid;            // 3456 words
        if (idx < 3456) {
            int pair = idx / 108;            // 0..31
            int pix  = idx - pair * 108;
            int r    = pix / 18;
            int cc   = pix - r * 18;
            int gq   = pair >> 2;
            int w    = pair & 3;
            int gr   = h0r + r - 1;
            gr = (gr < 0) ? 1 : ((gr > 63) ? 62 : gr);
            int gc   = w0c + cc - 1;
            gc = (gc < 0) ? 1 : ((gc > 63) ? 62 : gc);
            const float* p0 = xb + ((pair * 2) << 12) + (gr << 6) + gc;
            uint32_t b0 = __float_as_uint(p0[0]);
            uint32_t b1 = __float_as_uint(p0[4096]);
            uint32_t lo = (b0 + 0x7fffu + ((b0 >> 16) & 1u)) >> 16;
            uint32_t hi = (b1 + 0x7fffu + ((b1 >> 16) & 1u)) & 0xffff0000u;
            smem[gq * GS + r * RS + cc * 4 + w] = lo | hi;
        }
    }
    __syncthreads();

    const int wv   = __builtin_amdgcn_readfirstlane(tid >> 6);  // 0..3
    const int h8   = (hg * 4 + wv) << 3;     // this wave's head col base
    const int lane = tid & 63;
    const int tr   = lane >> 4;
    const int tc   = lane & 15;
    const uint32_t* xl4 = smem + tr * RS + tc * 4;  // 16B-aligned lane base
    const float scale = 0.35355339059327373f;  // 8^-0.5

    // ---- Phase A: q / q_ (one b128 center read per 8 channels) ----
    float q[8], qp[8];
#pragma unroll
    for (int d = 0; d < 8; ++d) {
        q[d]  = b_qk[h8 + d];
        qp[d] = b_qk[64 + h8 + d];
    }
#pragma unroll
    for (int g = 0; g < 8; ++g) {
        uint4 v = *(const uint4*)(xl4 + g * GS + RS + 4);  // (+1 row, +1 col)
#pragma unroll
        for (int w = 0; w < 4; ++w) {
            uint32_t dw = (&v.x)[w];
            float a0 = __uint_as_float(dw << 16);
            float a1 = __uint_as_float(dw & 0xffff0000u);
            const float* w0 = W_qk + ((8 * g + 2 * w) << 7) + h8;
            const float* w1 = w0 + 128;
#pragma unroll
            for (int d = 0; d < 8; ++d) {
                q[d]  = fmaf(a0, w0[d],      q[d]);
                qp[d] = fmaf(a0, w0[64 + d], qp[d]);
                q[d]  = fmaf(a1, w1[d],      q[d]);
                qp[d] = fmaf(a1, w1[64 + d], qp[d]);
            }
        }
    }
    float qv = 0.f, beta = 0.f;
#pragma unroll
    for (int d = 0; d < 8; ++d) {
        qv   = fmaf(q[d], qp[d], qv);
        beta = fmaf(q[d], b_kv[h8 + d], beta);
    }

    // ---- u = W_k^h . q ----
    float u[64];
#pragma unroll
    for (int c = 0; c < 64; ++c) {
        const float* w = W_kv + (c << 7) + h8;
        float s = q[0] * w[0];
#pragma unroll
        for (int d = 1; d < 8; ++d) s = fmaf(q[d], w[d], s);
        u[c] = s;
    }

    // ---- Scan 1: lg[t] += a * u[c]; 9 b128 reads per group of 8 ch ----
    float lgE[9], lgO[9];
#pragma unroll
    for (int t = 0; t < 9; ++t) { lgE[t] = 0.f; lgO[t] = 0.f; }
#pragma unroll
    for (int g = 0; g < 8; ++g) {
#pragma unroll
        for (int l = 0; l < 9; ++l) {
            const int wi = l / 3;
            const int wj = l - wi * 3;
            uint4 v = *(const uint4*)(xl4 + g * GS + wi * RS + wj * 4);
#pragma unroll
            for (int w = 0; w < 4; ++w) {
                uint32_t dw = (&v.x)[w];
                float a0 = __uint_as_float(dw << 16);
                float a1 = __uint_as_float(dw & 0xffff0000u);
                const int ch = 8 * g + 2 * w;
                const int f0 = 9 * ch + l, f1 = f0 + 9;
                const int t0 = f0 >> 6, c0 = f0 & 63;
                const int t1 = f1 >> 6, c1 = f1 & 63;
                if (f0 & 1) lgO[t0] = fmaf(a0, u[c0], lgO[t0]);
                else        lgE[t0] = fmaf(a0, u[c0], lgE[t0]);
                if (f1 & 1) lgO[t1] = fmaf(a1, u[c1], lgO[t1]);
                else        lgE[t1] = fmaf(a1, u[c1], lgE[t1]);
            }
        }
    }

    // ---- softmax over {9 tokens, global, qv} ----
    float pn[9], Pn = 0.f, pqv;
    {
        float lgs = 0.f, l2[11];
#pragma unroll
        for (int t = 0; t < 9; ++t) {
            float r = lgE[t] + lgO[t];
            lgs += r;
            l2[t] = (r + beta) * scale;
        }
        l2[9]  = (lgs * (1.f / 9.f) + beta) * scale;
        l2[10] = qv;
        float m = l2[0];
#pragma unroll
        for (int i = 1; i < 11; ++i) m = fmaxf(m, l2[i]);
        float pp[11], den = 0.f;
#pragma unroll
        for (int i = 0; i < 11; ++i) { pp[i] = __expf(l2[i] - m); den += pp[i]; }
        float inv = 1.f / den;
#pragma unroll
        for (int t = 0; t < 9; ++t) {
            pn[t] = (pp[t] + pp[9] * (1.f / 9.f)) * inv;
            Pn += pn[t];
        }
        pqv = pp[10] * inv;
    }

    // ---- Scan 2: y[c] += pn[t] * a ----
    float y[64];
#pragma unroll
    for (int c = 0; c < 64; ++c) y[c] = 0.f;
#pragma unroll
    for (int g = 0; g < 8; ++g) {
#pragma unroll
        for (int l = 0; l < 9; ++l) {
            const int wi = l / 3;
            const int wj = l - wi * 3;
            uint4 v = *(const uint4*)(xl4 + g * GS + wi * RS + wj * 4);
#pragma unroll
            for (int w = 0; w < 4; ++w) {
                uint32_t dw = (&v.x)[w];
                float a0 = __uint_as_float(dw << 16);
                float a1 = __uint_as_float(dw & 0xffff0000u);
                const int ch = 8 * g + 2 * w;
                const int f0 = 9 * ch + l, f1 = f0 + 9;
                const int t0 = f0 >> 6, c0 = f0 & 63;
                const int t1 = f1 >> 6, c1 = f1 & 63;
                y[c0] = fmaf(pn[t0], a0, y[c0]);
                y[c1] = fmaf(pn[t1], a1, y[c1]);
            }
        }
    }

    // ---- fold: o = W_v^T y + Pn*b_v + pqv*q_ ----
    float oA[8], oB[8];
#pragma unroll
    for (int d = 0; d < 8; ++d) {
        oA[d] = fmaf(pqv, qp[d], Pn * b_kv[64 + h8 + d]);
        oB[d] = 0.f;
    }
#pragma unroll
    for (int c = 0; c < 64; ++c) {
        const float* w = W_kv + (c << 7) + 64 + h8;
#pragma unroll
        for (int d = 0; d < 8; ++d) {
            if (c & 1) oB[d] = fmaf(y[c], w[d], oB[d]);
            else       oA[d] = fmaf(y[c], w[d], oA[d]);
        }
    }

    // ---- handoff through pre (aliased into smem), stride 33 ----
    __syncthreads();                        // all packed-tile reads complete
    float* pre = (float*)smem;              // [pixel][33]
#pragma unroll
    for (int d = 0; d < 8; ++d)
        pre[lane * 33 + (wv << 3) + d] = oA[d] + oB[d];
    __syncthreads();

    // ---- partial output projection over this block's 32 pre-channels ----
    const int j0 = wv << 4;
    float o2[16];
#pragma unroll
    for (int jj = 0; jj < 16; ++jj)
        o2[jj] = (hg == 0) ? b_proj[j0 + jj] : 0.f;
    const float* pl = pre + lane * 33;
#pragma unroll
    for (int c = 0; c < 32; ++c) {
        float a = pl[c];
        const float* w = W_proj + ((hg * 32 + c) << 6) + j0;
#pragma unroll
        for (int jj = 0; jj < 16; ++jj) o2[jj] = fmaf(a, w[jj], o2[jj]);
    }
    float* ob = out + (size_t)bb * (64 * 64 * 64);
    const int pr = h0r + tr, pc = w0c + tc;
#pragma unroll
    for (int jj = 0; jj < 16; ++jj)
        unsafeAtomicAdd(&ob[((j0 + jj) << 12) + (pr << 6) + pc], o2[jj]);
}

extern "C" void kernel_launch(void* const* d_in, const int* in_sizes, int n_in,
                              void* d_out, int out_size, void* d_ws, size_t ws_size,
                              hipStream_t stream)
{
    const float* x      = (const float*)d_in[0];
    const float* W_qk   = (const float*)d_in[1];
    const float* b_qk   = (const float*)d_in[2];
    const float* W_kv   = (const float*)d_in[3];
    const float* b_kv   = (const float*)d_in[4];
    const float* W_proj = (const float*)d_in[5];
    const float* b_proj = (const float*)d_in[6];
    float* out = (float*)d_out;

    hipMemsetAsync(out, 0, (size_t)out_size * sizeof(float), stream);
    pix_attn_main<<<1024, 256, 0, stream>>>(x, W_qk, b_qk, W_kv, b_kv,
                                            W_proj, b_proj, out);
}

// Round 12
// 75.830 us; speedup vs baseline: 3.6179x; 3.6179x over previous
//
#include <hip/hip_runtime.h>
#include <math.h>
#include <stdint.h>

// pix_attn R11: code-size attack (I-cache hypothesis) + f16 dot2/pk_fma scans.
//  - R10 post-mortem: removing fences -> VGPR 256 + spill storm. Fences stay.
//  - R9 gap analysis: wall 68us vs ~20us VALU pipe with 4 decorrelated
//    waves/SIMD -> shared-resource stall = instruction fetch (~40KB body).
//  - This round: body ~18KB. Scan1 via v_dot2_f32_f16 (pair (f,f+9) shares t
//    for 248/288 dwords; u2[c] = {u[c], u[(c+9)&63]}). Scan2 via v_pk_fma_f16
//    dual accumulators y2[c0] += (pn[t0],pn[t1])*a2; y[c] = lo(y2[c]) +
//    hi(y2[(c-9)&63]) afterwards (exact split-sum). Phase A and proj rolled
//    (#pragma unroll 1, uniform loop vars only).
//  - Tile now f16-packed (better than bf16: rel 5e-4). f16 y-accum err ~2e-3
//    << 7.3e-3 threshold.
//  - Rest = R9: grid 1024 (2 blocks/tile, 4 heads), memset+unsafeAtomicAdd,
//    u-trick / y-trick, wave = head, 256-thr blocks, fences per group.
//
// Scramble: f = 9*ch + l ; t = f>>6, c = f&63, (wi,wj) = (l/3, l%3).
// Pair in one dword: (f0, f0+9) with f0 = 9*(even ch)+l; boundary (t0!=t1)
// iff (f0&63) >= 55; t0 <= 7 in that case (f0 <= 566).

#define GS 432      // group stride (words) = 6 rows * 72
#define RS 72       // row stride (words) = 18 cols * 4

typedef _Float16 h2 __attribute__((ext_vector_type(2)));

__global__ __launch_bounds__(256, 1) void pix_attn_main(
    const float* __restrict__ x,
    const float* __restrict__ W_qk,
    const float* __restrict__ b_qk,
    const float* __restrict__ W_kv,
    const float* __restrict__ b_kv,
    const float* __restrict__ W_proj,
    const float* __restrict__ b_proj,
    float* __restrict__ out)
{
    __shared__ uint32_t smem[8 * GS];    // 13824 B packed tile; pre_s after

    const int tid = threadIdx.x;
    const int j    = blockIdx.x;
    const int g_   = j >> 4;
    const int tile = g_ * 8 + (j & 7);
    const int hg   = (j >> 3) & 1;
    const int bb   = tile >> 6;
    const int t_id = tile & 63;
    const int h0r  = (t_id >> 2) << 2;
    const int w0c  = (t_id & 3) << 4;

    // ---- stage packed tile: word(g,r,cc,w) = f16(ch=8g+2w) | f16(+1) ----
    const float* xb = x + (size_t)bb * (64 * 64 * 64);
#pragma unroll 1
    for (int it = 0; it < 14; ++it) {
        int idx = it * 256 + tid;            // 3456 words
        if (idx < 3456) {
            int pair = idx / 108;            // 0..31
            int pix  = idx - pair * 108;
            int r    = pix / 18;
            int cc   = pix - r * 18;
            int gq   = pair >> 2;
            int w    = pair & 3;
            int gr   = h0r + r - 1;
            gr = (gr < 0) ? 1 : ((gr > 63) ? 62 : gr);
            int gc   = w0c + cc - 1;
            gc = (gc < 0) ? 1 : ((gc > 63) ? 62 : gc);
            const float* p0 = xb + ((pair * 2) << 12) + (gr << 6) + gc;
            h2 pk = { (_Float16)p0[0], (_Float16)p0[4096] };
            smem[gq * GS + r * RS + cc * 4 + w] = __builtin_bit_cast(uint32_t, pk);
        }
    }
    __syncthreads();

    const int wv   = __builtin_amdgcn_readfirstlane(tid >> 6);  // 0..3
    const int h8   = (hg * 4 + wv) << 3;     // this wave's head col base
    const int lane = tid & 63;
    const int tr   = lane >> 4;
    const int tc   = lane & 15;
    const uint32_t* xl4 = smem + tr * RS + tc * 4;  // 16B-aligned lane base
    const float scale = 0.35355339059327373f;  // 8^-0.5

    // ---- Phase A (rolled over g): q / q_ ----
    float q[8], qp[8];
#pragma unroll
    for (int d = 0; d < 8; ++d) {
        q[d]  = b_qk[h8 + d];
        qp[d] = b_qk[64 + h8 + d];
    }
#pragma unroll 1
    for (int g = 0; g < 8; ++g) {
        uint4 v = *(const uint4*)(xl4 + g * GS + RS + 4);  // center (+1r,+1c)
#pragma unroll
        for (int w = 0; w < 4; ++w) {
            h2 hv = __builtin_bit_cast(h2, (&v.x)[w]);
            float a0 = (float)hv.x;
            float a1 = (float)hv.y;
            const float* w0 = W_qk + ((8 * g + 2 * w) << 7) + h8;
            const float* w1 = w0 + 128;
#pragma unroll
            for (int d = 0; d < 8; ++d) {
                q[d]  = fmaf(a0, w0[d],      q[d]);
                qp[d] = fmaf(a0, w0[64 + d], qp[d]);
                q[d]  = fmaf(a1, w1[d],      q[d]);
                qp[d] = fmaf(a1, w1[64 + d], qp[d]);
            }
        }
        __builtin_amdgcn_sched_barrier(0);
    }
    float qv = 0.f, beta = 0.f;
#pragma unroll
    for (int d = 0; d < 8; ++d) {
        qv   = fmaf(q[d], qp[d], qv);
        beta = fmaf(q[d], b_kv[h8 + d], beta);
    }
    __builtin_amdgcn_sched_barrier(0);

    // ---- u = W_k^h . q ; build u2[c] = {u[c], u[(c+9)&63]} incrementally ----
    float uf[64];
    h2 u2[64];
#pragma unroll
    for (int c = 0; c < 64; ++c) {
        const float* w = W_kv + (c << 7) + h8;
        float s = q[0] * w[0];
#pragma unroll
        for (int d = 1; d < 8; ++d) s = fmaf(q[d], w[d], s);
        uf[c] = s;
        if (c >= 9) u2[c - 9] = h2{ (_Float16)uf[c - 9], (_Float16)uf[c] };
        if ((c & 15) == 15) __builtin_amdgcn_sched_barrier(0);
    }
#pragma unroll
    for (int c = 55; c < 64; ++c)
        u2[c] = h2{ (_Float16)uf[c], (_Float16)uf[c + 9 - 64] };
    __builtin_amdgcn_sched_barrier(0);

    // ---- Scan 1: lg[t] += dot2(a2, u2[c0]); boundary pairs scalar ----
    float lg[9];
#pragma unroll
    for (int t = 0; t < 9; ++t) lg[t] = 0.f;
#pragma unroll
    for (int g = 0; g < 8; ++g) {
#pragma unroll
        for (int l = 0; l < 9; ++l) {
            const int wi = l / 3;
            const int wj = l - wi * 3;
            uint4 v = *(const uint4*)(xl4 + g * GS + wi * RS + wj * 4);
#pragma unroll
            for (int w = 0; w < 4; ++w) {
                h2 hv = __builtin_bit_cast(h2, (&v.x)[w]);
                const int f0 = 9 * (8 * g + 2 * w) + l;
                const int c0 = f0 & 63;
                const int t0 = f0 >> 6;
                if (c0 < 55) {
                    lg[t0] = __builtin_amdgcn_fdot2(hv, u2[c0], lg[t0], false);
                } else {
                    lg[t0]     = fmaf((float)hv.x, (float)u2[c0].x, lg[t0]);
                    lg[t0 + 1] = fmaf((float)hv.y, (float)u2[c0].y, lg[t0 + 1]);
                }
            }
        }
        __builtin_amdgcn_sched_barrier(0);
    }

    // ---- softmax over {9 tokens, global, qv} ----
    float pn[9], Pn = 0.f, pqv;
    {
        float lgs = 0.f, l2[11];
#pragma unroll
        for (int t = 0; t < 9; ++t) {
            lgs += lg[t];
            l2[t] = (lg[t] + beta) * scale;
        }
        l2[9]  = (lgs * (1.f / 9.f) + beta) * scale;
        l2[10] = qv;
        float m = l2[0];
#pragma unroll
        for (int i = 1; i < 11; ++i) m = fmaxf(m, l2[i]);
        float pp[11], den = 0.f;
#pragma unroll
        for (int i = 0; i < 11; ++i) { pp[i] = __expf(l2[i] - m); den += pp[i]; }
        float inv = 1.f / den;
#pragma unroll
        for (int t = 0; t < 9; ++t) {
            pn[t] = (pp[t] + pp[9] * (1.f / 9.f)) * inv;
            Pn += pn[t];
        }
        pqv = pp[10] * inv;
    }
    h2 pn2[9], pn2b[8];
#pragma unroll
    for (int t = 0; t < 9; ++t) pn2[t] = h2{ (_Float16)pn[t], (_Float16)pn[t] };
#pragma unroll
    for (int t = 0; t < 8; ++t) pn2b[t] = h2{ (_Float16)pn[t], (_Float16)pn[t + 1] };
    __builtin_amdgcn_sched_barrier(0);

    // ---- Scan 2: y2[c0] += (pn[t0],pn[t1]) * a2  (pk_fma, dual accum) ----
    h2 y2[64];
#pragma unroll
    for (int c = 0; c < 64; ++c) y2[c] = h2{ (_Float16)0.f, (_Float16)0.f };
#pragma unroll
    for (int g = 0; g < 8; ++g) {
#pragma unroll
        for (int l = 0; l < 9; ++l) {
            const int wi = l / 3;
            const int wj = l - wi * 3;
            uint4 v = *(const uint4*)(xl4 + g * GS + wi * RS + wj * 4);
#pragma unroll
            for (int w = 0; w < 4; ++w) {
                h2 a = __builtin_bit_cast(h2, (&v.x)[w]);
                const int f0 = 9 * (8 * g + 2 * w) + l;
                const int c0 = f0 & 63;
                const int t0 = f0 >> 6;
                h2 m2 = (c0 < 55) ? pn2[t0] : pn2b[t0];
                y2[c0] = y2[c0] + m2 * a;
            }
        }
        __builtin_amdgcn_sched_barrier(0);
    }

    // ---- reconstruct y[c] = lo(y2[c]) + hi(y2[(c-9)&63]) ----
    float y[64];
#pragma unroll
    for (int c = 0; c < 64; ++c)
        y[c] = (float)y2[c].x + (float)y2[(c + 55) & 63].y;
    __builtin_amdgcn_sched_barrier(0);

    // ---- fold: o = W_v^T y + Pn*b_v + pqv*q_ ----
    float oA[8], oB[8];
#pragma unroll
    for (int d = 0; d < 8; ++d) {
        oA[d] = fmaf(pqv, qp[d], Pn * b_kv[64 + h8 + d]);
        oB[d] = 0.f;
    }
#pragma unroll
    for (int c = 0; c < 64; ++c) {
        const float* w = W_kv + (c << 7) + 64 + h8;
#pragma unroll
        for (int d = 0; d < 8; ++d) {
            if (c & 1) oB[d] = fmaf(y[c], w[d], oB[d]);
            else       oA[d] = fmaf(y[c], w[d], oA[d]);
        }
        if ((c & 15) == 15) __builtin_amdgcn_sched_barrier(0);
    }

    // ---- handoff through pre (aliased into smem), stride 33 ----
    __syncthreads();                        // all packed-tile reads complete
    float* pre = (float*)smem;              // [pixel][33]
#pragma unroll
    for (int d = 0; d < 8; ++d)
        pre[lane * 33 + (wv << 3) + d] = oA[d] + oB[d];
    __syncthreads();

    // ---- partial output projection (rolled over c) ----
    const int j0 = wv << 4;
    float o2[16];
#pragma unroll
    for (int jj = 0; jj < 16; ++jj)
        o2[jj] = (hg == 0) ? b_proj[j0 + jj] : 0.f;
    const float* pl = pre + lane * 33;
#pragma unroll 1
    for (int c = 0; c < 32; ++c) {
        float a = pl[c];
        const float* w = W_proj + ((hg * 32 + c) << 6) + j0;
#pragma unroll
        for (int jj = 0; jj < 16; ++jj) o2[jj] = fmaf(a, w[jj], o2[jj]);
    }
    float* ob = out + (size_t)bb * (64 * 64 * 64);
    const int pr = h0r + tr, pc = w0c + tc;
#pragma unroll
    for (int jj = 0; jj < 16; ++jj)
        unsafeAtomicAdd(&ob[((j0 + jj) << 12) + (pr << 6) + pc], o2[jj]);
}

extern "C" void kernel_launch(void* const* d_in, const int* in_sizes, int n_in,
                              void* d_out, int out_size, void* d_ws, size_t ws_size,
                              hipStream_t stream)
{
    const float* x      = (const float*)d_in[0];
    const float* W_qk   = (const float*)d_in[1];
    const float* b_qk   = (const float*)d_in[2];
    const float* W_kv   = (const float*)d_in[3];
    const float* b_kv   = (const float*)d_in[4];
    const float* W_proj = (const float*)d_in[5];
    const float* b_proj = (const float*)d_in[6];
    float* out = (float*)d_out;

    hipMemsetAsync(out, 0, (size_t)out_size * sizeof(float), stream);
    pix_attn_main<<<1024, 256, 0, stream>>>(x, W_qk, b_qk, W_kv, b_kv,
                                            W_proj, b_proj, out);
}